// Round 1
// baseline (32.721 us; speedup 1.0000x reference)
//
#include <hip/hip_runtime.h>
#include <math.h>

// Problem constants (match reference)
constexpr int   BB   = 32;
constexpr int   NF   = 500;
constexpr int   FS   = 240;
constexpr int   TT   = NF * FS;      // 120000
constexpr int   HH   = 8;
constexpr float ALPHA = 0.1f;

// ---------------------------------------------------------------------------
// Kernel A: per-batch-row frame-level phase prefix (in revolutions, f64).
// ws2[b*NF+f] = { frac(prefix_rev), dphi_rev (f32) }
// grid = BB blocks, block = 64 threads (1 wave). Each lane owns 8 frames.
// ---------------------------------------------------------------------------
__global__ __launch_bounds__(64) void frame_scan(const float* __restrict__ f0s,
                                                 float2* __restrict__ ws2) {
    const int b    = blockIdx.x;
    const int lane = threadIdx.x;

    const float  TWO_PI_F = 6.28318530717958647692f;   // rounds to f32 like np's 2.0*np.pi scalar
    const double INV_2PI  = 0.15915494309189533576;

    double d[8];
    double sum = 0.0;
#pragma unroll
    for (int i = 0; i < 8; ++i) {
        const int f = lane * 8 + i;
        const float f0   = (f < NF) ? f0s[b * NF + f] : 0.0f;
        const float dphi = (TWO_PI_F * f0) / 24000.0f;   // f32, matches np order
        d[i] = (double)dphi * INV_2PI;                   // revolutions per sample
        sum += d[i];
    }

    // wave-wide inclusive scan of per-lane frame sums (x240 samples per frame)
    const double mine = sum * 240.0;
    double run = mine;
    for (int delta = 1; delta < 64; delta <<= 1) {
        const double o = __shfl_up(run, delta, 64);
        if (lane >= delta) run += o;
    }
    double acc = run - mine;   // exclusive prefix for this lane's first frame

#pragma unroll
    for (int i = 0; i < 8; ++i) {
        const int f = lane * 8 + i;
        if (f < NF) {
            const double fr = acc - rint(acc);           // frac in [-0.5, 0.5]
            ws2[b * NF + f] = make_float2((float)fr, (float)d[i]);
        }
        acc += d[i] * 240.0;
    }
}

// ---------------------------------------------------------------------------
// Kernel B: fused harmonic synth. 4 consecutive samples per thread
// (a group of 4 never crosses a frame boundary since 240 % 4 == 0).
// ---------------------------------------------------------------------------
__device__ __forceinline__ float sin_rev(float fr) {
    // fr in [-0.5, 0.5] revolutions
#if __has_builtin(__builtin_amdgcn_sinf)
    return __builtin_amdgcn_sinf(fr);        // v_sin_f32: D = sin(S0 * 2pi)
#else
    return __sinf(fr * 6.28318530717958647692f);
#endif
}

__global__ __launch_bounds__(256) void synth(const float* __restrict__ phi,
                                             const float* __restrict__ amp,
                                             const float* __restrict__ noise,
                                             const float2* __restrict__ ws2,
                                             float* __restrict__ out) {
    const int g  = blockIdx.x * 256 + threadIdx.x;   // 0 .. BB*TT/4-1
    const int s4 = g * 4;
    const int b  = s4 / TT;
    const int t  = s4 - b * TT;
    const int f  = t / FS;
    const int j  = t - f * FS;                       // multiple of 4

    const float2 fd = ws2[b * NF + f];
    const float  dr = fd.y;                          // dphi in revolutions (f32)
    const bool   voiced = (dr > 0.0f);

    float cs[4];
    cs[0] = fd.x + (float)(j + 1) * dr;              // inclusive cumsum semantics
    cs[1] = cs[0] + dr;
    cs[2] = cs[1] + dr;
    cs[3] = cs[2] + dr;

    const float INV2PIf = 0.15915494309189533576f;

    float sdot[4] = {0.f, 0.f, 0.f, 0.f};
    float ndot[4] = {0.f, 0.f, 0.f, 0.f};
    float kcs[4]  = {0.f, 0.f, 0.f, 0.f};

#pragma unroll
    for (int h = 0; h < HH; ++h) {
        const float a  = amp[h];
        const float ph = phi[h] * INV2PIf;
        const float4 nh = *reinterpret_cast<const float4*>(
            noise + ((size_t)(h * BB + b) * TT + t));

        ndot[0] = fmaf(a, nh.x, ndot[0]);
        ndot[1] = fmaf(a, nh.y, ndot[1]);
        ndot[2] = fmaf(a, nh.z, ndot[2]);
        ndot[3] = fmaf(a, nh.w, ndot[3]);

#pragma unroll
        for (int e = 0; e < 4; ++e) {
            kcs[e] += cs[e];                         // k = h+1 times cs
            const float r  = kcs[e] + ph;
            const float fr = r - rintf(r);           // reduce to [-0.5, 0.5] rev
            sdot[e] = fmaf(a, sin_rev(fr), sdot[e]);
        }
    }

    const float a8 = amp[HH];
    const float UV = (float)(0.1 / (3.0 * 0.003));   // ALPHA / (3*SIGMA)

    float4 o;
    float* op = reinterpret_cast<float*>(&o);
#pragma unroll
    for (int e = 0; e < 4; ++e) {
        const float x = voiced ? fmaf(ALPHA, sdot[e], ndot[e]) : UV * ndot[e];
        op[e] = tanhf(x + a8);
    }
    *reinterpret_cast<float4*>(out + (size_t)b * TT + t) = o;
}

// ---------------------------------------------------------------------------
extern "C" void kernel_launch(void* const* d_in, const int* in_sizes, int n_in,
                              void* d_out, int out_size, void* d_ws, size_t ws_size,
                              hipStream_t stream) {
    const float* f0s   = (const float*)d_in[0];   // [32, 500]
    const float* phi   = (const float*)d_in[1];   // [8]
    const float* amp   = (const float*)d_in[2];   // [9]
    const float* noise = (const float*)d_in[3];   // [8, 32, 120000]
    float* out = (float*)d_out;                   // [32, 120000]
    float2* ws2 = (float2*)d_ws;                  // [32, 500] float2 = 128 KB

    frame_scan<<<BB, 64, 0, stream>>>(f0s, ws2);

    const int nthreads = BB * TT / 4;             // 960000
    synth<<<nthreads / 256, 256, 0, stream>>>(phi, amp, noise, ws2, out);
}

// Round 2
// 30.102 us; speedup vs baseline: 1.0870x; 1.0870x over previous
//
#include <hip/hip_runtime.h>
#include <math.h>

// Problem constants (match reference)
constexpr int   BB    = 32;
constexpr int   NF    = 500;
constexpr int   FS    = 240;
constexpr int   TT    = NF * FS;     // 120000
constexpr int   HH    = 8;
constexpr float ALPHA = 0.1f;

constexpr int SPT = 8;               // samples per thread (240 % 8 == 0)
constexpr int BLK = 256;

__device__ __forceinline__ float sin_rev(float fr) {
    // fr in [-0.5, 0.5] revolutions; v_sin_f32: D = sin(S0 * 2pi)
#if __has_builtin(__builtin_amdgcn_sinf)
    return __builtin_amdgcn_sinf(fr);
#else
    return __sinf(fr * 6.28318530717958647692f);
#endif
}

// ---------------------------------------------------------------------------
// Fused kernel. grid = (ceil(TT/SPT/BLK), BB). Wave 0 of each block
// recomputes the row's frame-level phase prefix (f64, revolutions) into LDS
// (f0 is 64 KB total -> L2/L3 resident; redundancy costs no HBM traffic).
// Then each thread synthesizes 8 consecutive samples (never crossing a frame).
// ---------------------------------------------------------------------------
__global__ __launch_bounds__(BLK) void synth_fused(const float* __restrict__ f0s,
                                                   const float* __restrict__ phi,
                                                   const float* __restrict__ amp,
                                                   const float* __restrict__ noise,
                                                   float* __restrict__ out) {
    const int b   = blockIdx.y;
    const int tid = threadIdx.x;

    __shared__ float2 sfr[NF];   // {frac(prefix_rev) at frame start, dphi_rev}

    if (tid < 64) {
        const int lane = tid;
        const float  TWO_PI_F = 6.28318530717958647692f;
        const double INV_2PI  = 0.15915494309189533576;

        double d[8];
        double sum = 0.0;
#pragma unroll
        for (int i = 0; i < 8; ++i) {
            const int f = lane * 8 + i;
            const float f0   = (f < NF) ? f0s[b * NF + f] : 0.0f;
            const float dphi = (TWO_PI_F * f0) / 24000.0f;   // f32, matches np op order
            d[i] = (double)dphi * INV_2PI;                   // revolutions/sample
            sum += d[i];
        }

        const double mine = sum * 240.0;
        double run = mine;
        for (int delta = 1; delta < 64; delta <<= 1) {
            const double o = __shfl_up(run, delta, 64);
            if (lane >= delta) run += o;
        }
        double acc = run - mine;   // exclusive prefix at this lane's first frame

#pragma unroll
        for (int i = 0; i < 8; ++i) {
            const int f = lane * 8 + i;
            if (f < NF) {
                const double fr = acc - rint(acc);
                sfr[f] = make_float2((float)fr, (float)d[i]);
            }
            acc += d[i] * 240.0;
        }
    }
    __syncthreads();

    const int t = (blockIdx.x * BLK + tid) * SPT;
    if (t >= TT) return;

    const int f = t / FS;
    const int j = t - f * FS;                 // multiple of 8, within one frame

    const float2 fd = sfr[f];
    const float  dr = fd.y;
    const bool   voiced = (dr > 0.0f);

    float cs[SPT];
    cs[0] = fd.x + (float)(j + 1) * dr;       // inclusive cumsum semantics
#pragma unroll
    for (int e = 1; e < SPT; ++e) cs[e] = cs[e - 1] + dr;

    const float INV2PIf = 0.15915494309189533576f;

    float sdot[SPT], ndot[SPT], kcs[SPT];
#pragma unroll
    for (int e = 0; e < SPT; ++e) { sdot[e] = 0.f; ndot[e] = 0.f; kcs[e] = 0.f; }

    const size_t base = (size_t)b * TT + t;

#pragma unroll
    for (int h = 0; h < HH; ++h) {
        const float a  = amp[h];
        const float ph = phi[h] * INV2PIf;
        const float4* np4 = reinterpret_cast<const float4*>(
            noise + (size_t)h * (BB * (size_t)TT) + base);
        const float4 n0 = np4[0];
        const float4 n1 = np4[1];

        ndot[0] = fmaf(a, n0.x, ndot[0]);
        ndot[1] = fmaf(a, n0.y, ndot[1]);
        ndot[2] = fmaf(a, n0.z, ndot[2]);
        ndot[3] = fmaf(a, n0.w, ndot[3]);
        ndot[4] = fmaf(a, n1.x, ndot[4]);
        ndot[5] = fmaf(a, n1.y, ndot[5]);
        ndot[6] = fmaf(a, n1.z, ndot[6]);
        ndot[7] = fmaf(a, n1.w, ndot[7]);

#pragma unroll
        for (int e = 0; e < SPT; ++e) {
            kcs[e] += cs[e];                  // k = (h+1) * cs
            const float r  = kcs[e] + ph;
            const float fr = r - rintf(r);    // reduce to [-0.5, 0.5] rev
            sdot[e] = fmaf(a, sin_rev(fr), sdot[e]);
        }
    }

    const float a8 = amp[HH];
    const float UV = (float)(0.1 / (3.0 * 0.003));   // ALPHA / (3*SIGMA)

    float4 o0, o1;
    float* op = reinterpret_cast<float*>(&o0);       // o0,o1 contiguous? no — do separately
    float tmp[SPT];
#pragma unroll
    for (int e = 0; e < SPT; ++e) {
        const float x = voiced ? fmaf(ALPHA, sdot[e], ndot[e]) : UV * ndot[e];
        tmp[e] = tanhf(x + a8);
    }
    o0 = make_float4(tmp[0], tmp[1], tmp[2], tmp[3]);
    o1 = make_float4(tmp[4], tmp[5], tmp[6], tmp[7]);
    float4* ov = reinterpret_cast<float4*>(out + base);
    ov[0] = o0;
    ov[1] = o1;
    (void)op;
}

// ---------------------------------------------------------------------------
extern "C" void kernel_launch(void* const* d_in, const int* in_sizes, int n_in,
                              void* d_out, int out_size, void* d_ws, size_t ws_size,
                              hipStream_t stream) {
    const float* f0s   = (const float*)d_in[0];   // [32, 500]
    const float* phi   = (const float*)d_in[1];   // [8]
    const float* amp   = (const float*)d_in[2];   // [9]
    const float* noise = (const float*)d_in[3];   // [8, 32, 120000]
    float* out = (float*)d_out;                   // [32, 120000]

    const int blocks_x = (TT / SPT + BLK - 1) / BLK;   // 59
    dim3 grid(blocks_x, BB);
    synth_fused<<<grid, BLK, 0, stream>>>(f0s, phi, amp, noise, out);
}